// Round 2
// baseline (195.444 us; speedup 1.0000x reference)
//
#include <hip/hip_runtime.h>
#include <stdint.h>

typedef __bf16 bf16_t;
typedef __bf16 bf16x8 __attribute__((ext_vector_type(8)));
typedef float f32x4 __attribute__((ext_vector_type(4)));
typedef float f32x16 __attribute__((ext_vector_type(16)));

#define DEV __device__ __forceinline__

DEV void gload_lds16(const void* g, void* lds) {
  __builtin_amdgcn_global_load_lds(
      (const __attribute__((address_space(1))) uint32_t*)g,
      (__attribute__((address_space(3))) uint32_t*)lds, 16, 0, 0);
}

DEV float fexp2(float x) {
#if __has_builtin(__builtin_amdgcn_exp2f)
  return __builtin_amdgcn_exp2f(x);
#else
  return exp2f(x);
#endif
}

DEV uint32_t pk_bf16(float a, float b) {
  uint32_t lo = (uint32_t)__builtin_bit_cast(uint16_t, (bf16_t)a);
  uint32_t hi = (uint32_t)__builtin_bit_cast(uint16_t, (bf16_t)b);
  return lo | (hi << 16);
}

// ---------------------------------------------------------------- K0: hs -> bf16
__global__ __launch_bounds__(256) void cvt_hs(const float* __restrict__ x,
                                              bf16_t* __restrict__ y) {
  int i = blockIdx.x * 256 + threadIdx.x;  // 3072*256 threads, 4 elems each (exact)
  float4 v = ((const float4*)x)[i];
  ((uint2*)y)[i] = make_uint2(pk_bf16(v.x, v.y), pk_bf16(v.z, v.w));
}

// ------------------------------------------- K1: W[k][n] (x3) -> WT[n][k] bf16
__global__ __launch_bounds__(256) void cvt_w(const float* __restrict__ Wq,
                                             const float* __restrict__ Wk,
                                             const float* __restrict__ Wv,
                                             bf16_t* __restrict__ WT) {
  __shared__ float T[32][36];
  const int bx = blockIdx.x;   // n tile 0..71 (over 2304)
  const int by = blockIdx.y;   // k tile 0..23 (over 768)
  const int p = bx / 24;
  const float* W = (p == 0) ? Wq : ((p == 1) ? Wk : Wv);
  const int n0 = bx * 32, nn0 = n0 - p * 768, k0 = by * 32;
  const int t = threadIdx.x;
  {
    int r = t >> 3, c4 = (t & 7) * 4;
    float4 v = *(const float4*)&W[(size_t)(k0 + r) * 768 + nn0 + c4];
    T[r][c4 + 0] = v.x; T[r][c4 + 1] = v.y; T[r][c4 + 2] = v.z; T[r][c4 + 3] = v.w;
  }
  __syncthreads();
  {
    int nr = t >> 3, kc = (t & 7) * 4;
    uint32_t lo = pk_bf16(T[kc + 0][nr], T[kc + 1][nr]);
    uint32_t hi = pk_bf16(T[kc + 2][nr], T[kc + 3][nr]);
    *(uint2*)&WT[(size_t)(n0 + nr) * 768 + k0 + kc] = make_uint2(lo, hi);
  }
}

// ------------------------------------------------- K2: C[4096,2304] = A @ W (+b)
// m97-style: 128x128 tile, BK=64, global_load_lds w=16, mfma 16x16x32 bf16.
// Epilogue scatters into per-head Q[bh][s][64], K[bh][s][64] bf16, and V
// DIRECTLY TRANSPOSED as VT[bh][d][s] bf16 (so attention needs no transpose).
__global__ __launch_bounds__(256) void gemm_qkv(
    const bf16_t* __restrict__ A, const bf16_t* __restrict__ Wt,
    const float* __restrict__ bq, const float* __restrict__ bk,
    const float* __restrict__ bv, bf16_t* __restrict__ Qo,
    bf16_t* __restrict__ Ko, bf16_t* __restrict__ VTo) {
  __shared__ bf16_t As[128 * 64];
  __shared__ bf16_t Bs[128 * 64];
  const int bx = blockIdx.x;  // 0..17 (n)
  const int by = blockIdx.y;  // 0..31 (m)
  const int m0 = by * 128, n0 = bx * 128;
  const int tid = threadIdx.x, w = tid >> 6, lane = tid & 63;
  const int mw = (w & 1) * 64, nw = (w >> 1) * 64;
  const int quad = lane >> 4, col = lane & 15;

  f32x4 acc[4][4];
  for (int i = 0; i < 4; i++)
    for (int j = 0; j < 4; j++) acc[i][j] = (f32x4){0.f, 0.f, 0.f, 0.f};

  const int srow = w * 32 + (lane >> 3);  // + i*8
  const int scol = (lane & 7) * 8;
  const bf16_t* ag = A + (size_t)(m0 + srow) * 768 + scol;
  const bf16_t* bg = Wt + (size_t)(n0 + srow) * 768 + scol;

  for (int kk = 0; kk < 12; ++kk) {
    const int k0 = kk * 64;
    __syncthreads();
#pragma unroll
    for (int i = 0; i < 4; i++) {
      gload_lds16(ag + (size_t)i * 8 * 768 + k0, As + (w * 32 + i * 8) * 64);
      gload_lds16(bg + (size_t)i * 8 * 768 + k0, Bs + (w * 32 + i * 8) * 64);
    }
    __syncthreads();
#pragma unroll
    for (int ks = 0; ks < 2; ++ks) {
      bf16x8 af[4], bf[4];
#pragma unroll
      for (int mt = 0; mt < 4; ++mt)
        af[mt] = *(const bf16x8*)&As[(mw + mt * 16 + col) * 64 + ks * 32 + quad * 8];
#pragma unroll
      for (int nt = 0; nt < 4; ++nt)
        bf[nt] = *(const bf16x8*)&Bs[(nw + nt * 16 + col) * 64 + ks * 32 + quad * 8];
#pragma unroll
      for (int mt = 0; mt < 4; ++mt)
#pragma unroll
        for (int nt = 0; nt < 4; ++nt)
          acc[mt][nt] = __builtin_amdgcn_mfma_f32_16x16x32_bf16(
              af[mt], bf[nt], acc[mt][nt], 0, 0, 0);
    }
  }

  const int p = bx / 6;  // 6 n-tiles per projection
  const float* bp = (p == 0) ? bq : ((p == 1) ? bk : bv);
#pragma unroll
  for (int nt = 0; nt < 4; nt++) {
    int n = n0 + nw + nt * 16 + col;
    int nn = n - p * 768;
    int head = nn >> 6, hd = nn & 63;
    float bias = bp[nn];
#pragma unroll
    for (int mt = 0; mt < 4; mt++) {
      int mbase = m0 + mw + mt * 16 + quad * 4;
#pragma unroll
      for (int r = 0; r < 4; r++) {
        int mm = mbase + r;
        int b = mm >> 11, s = mm & 2047;
        bf16_t val = (bf16_t)(acc[mt][nt][r] + bias);
        if (p == 0) {
          Qo[(size_t)((b * 12 + head) * 2048 + s) * 64 + hd] = val;
        } else if (p == 1) {
          Ko[(size_t)((b * 12 + head) * 2048 + s) * 64 + hd] = val;
        } else {
          // transposed: VT[bh][d][s]
          VTo[((size_t)(b * 12 + head) * 64 + hd) * 2048 + s] = val;
        }
      }
    }
  }
}

// ---------------------------------------------------------------- K3: attention
// 2 waves/WG, 32 queries/wave, 64-key blocks. S^T = K@Q^T (32x32x16 MFMA):
// C cols = query = lane&31 -> per-lane softmax stats + one shfl_xor(32).
// P^T -> LDS [q][key] (XOR-swizzled) -> A-operand of P@V; V^T tiles as B-operand.
__global__ __launch_bounds__(128) void attn(const bf16_t* __restrict__ Q,
                                            const bf16_t* __restrict__ K,
                                            const bf16_t* __restrict__ VT,
                                            float* __restrict__ out) {
  __shared__ bf16_t Kl[64 * 64];      // [key][d], 16B chunks XOR-swizzled by row&7
  __shared__ bf16_t Vl[64 * 64];      // [d][key], same swizzle
  __shared__ bf16_t Pl[2][32 * 64];   // per-wave [q][key], same swizzle
  const int qt = blockIdx.x;  // 0..31
  const int bh = blockIdx.y;  // 0..23
  const int b = bh / 12, head = bh % 12;
  const int tid = threadIdx.x, wv = tid >> 6, lane = tid & 63;
  const int lq = lane & 31, half = lane >> 5;
  const int q0 = qt * 64 + wv * 32;

  bf16x8 qf[4];  // B-operand frags of Q (per-lane query = lq), register resident
  {
    const bf16_t* qp = Q + (size_t)(bh * 2048 + q0 + lq) * 64 + half * 8;
#pragma unroll
    for (int ks = 0; ks < 4; ++ks) qf[ks] = *(const bf16x8*)(qp + ks * 16);
  }

  f32x16 oacc[2];
  for (int i = 0; i < 16; i++) { oacc[0][i] = 0.f; oacc[1][i] = 0.f; }
  float m_run = -1e30f, l_run = 0.f;

  const int srow_i = lane >> 3;  // + i*8
  const int scc = lane & 7;
  const bf16_t* gK = K + (size_t)(bh * 2048) * 64;
  const bf16_t* gV = VT + (size_t)(bh * 64) * 2048;

  for (int kb = 0; kb < 32; ++kb) {
    const int k0 = kb * 64;
    __syncthreads();
    if (wv == 0) {
#pragma unroll
      for (int i = 0; i < 8; i++) {
        int row = i * 8 + srow_i;
        int cg = scc ^ (row & 7);  // global chunk feeding swizzled LDS slot
        gload_lds16(gK + (size_t)(k0 + row) * 64 + cg * 8, Kl + i * 8 * 64);
      }
    } else {
#pragma unroll
      for (int i = 0; i < 8; i++) {
        int row = i * 8 + srow_i;
        int cg = scc ^ (row & 7);
        gload_lds16(gV + (size_t)row * 2048 + k0 + cg * 8, Vl + i * 8 * 64);
      }
    }
    __syncthreads();

    // S^T[key][q] = K_blk @ Q^T
    f32x16 sacc[2];
    for (int i = 0; i < 16; i++) { sacc[0][i] = 0.f; sacc[1][i] = 0.f; }
#pragma unroll
    for (int t = 0; t < 2; t++) {
      const int row = t * 32 + lq;  // A m = lane&31 = key within tile
#pragma unroll
      for (int ks = 0; ks < 4; ++ks) {
        bf16x8 a = *(const bf16x8*)&Kl[row * 64 + (((2 * ks + half) ^ (row & 7)) * 8)];
        sacc[t] = __builtin_amdgcn_mfma_f32_32x32x16_bf16(a, qf[ks], sacc[t], 0, 0, 0);
      }
    }

    // online softmax, per query (= lane column), scale 1/sqrt(64) folded into exp2
    float mb = -1e30f;
#pragma unroll
    for (int t = 0; t < 2; t++)
#pragma unroll
      for (int r = 0; r < 16; r++) mb = fmaxf(mb, sacc[t][r]);
    mb = fmaxf(mb, __shfl_xor(mb, 32));
    const float mnew = fmaxf(m_run, mb);
    const float cc = 0.18033688011112042f;  // log2(e)/sqrt(64)
    const float alpha = fexp2((m_run - mnew) * cc);
    float ps = 0.f;
#pragma unroll
    for (int t = 0; t < 2; t++)
#pragma unroll
      for (int r = 0; r < 16; r++) {
        float pv = fexp2((sacc[t][r] - mnew) * cc);
        sacc[t][r] = pv;
        ps += pv;
      }
    ps += __shfl_xor(ps, 32);
    l_run = l_run * alpha + ps;
    m_run = mnew;

    // P^T -> Pl[wv] as [q][key] (swizzled); keys (r&3)+8*(r>>2)+4*half+32t
    bf16_t* pw = &Pl[wv][0];
#pragma unroll
    for (int t = 0; t < 2; t++)
#pragma unroll
      for (int a2 = 0; a2 < 4; a2++) {
        uint32_t lo = pk_bf16(sacc[t][4 * a2 + 0], sacc[t][4 * a2 + 1]);
        uint32_t hi = pk_bf16(sacc[t][4 * a2 + 2], sacc[t][4 * a2 + 3]);
        char* db = (char*)pw + lq * 128 + (((4 * t + a2) ^ (lq & 7)) * 16) + half * 8;
        *(uint2*)db = make_uint2(lo, hi);
      }

    // rescale O accumulator rows (C rows q_r = (r&3)+8*(r>>2)+4*half)
#pragma unroll
    for (int r = 0; r < 16; r++) {
      int q_r = (r & 3) + 8 * (r >> 2) + 4 * half;
      int ai = __builtin_amdgcn_ds_bpermute(q_r << 2, __builtin_bit_cast(int, alpha));
      float ar = __builtin_bit_cast(float, ai);
      oacc[0][r] *= ar;
      oacc[1][r] *= ar;
    }

    // O[q][d] += P[q][k] * V[k][d]; A = P frags from Pl, B = V^T frags from Vl
#pragma unroll
    for (int s = 0; s < 4; s++) {
      bf16x8 pa = *(const bf16x8*)&Pl[wv][lq * 64 + (((2 * s + half) ^ (lq & 7)) * 8)];
#pragma unroll
      for (int dt = 0; dt < 2; dt++) {
        const int vr = dt * 32 + lq;  // B n = lane&31 = d within tile
        bf16x8 vb = *(const bf16x8*)&Vl[vr * 64 + (((2 * s + half) ^ (vr & 7)) * 8)];
        oacc[dt] = __builtin_amdgcn_mfma_f32_32x32x16_bf16(pa, vb, oacc[dt], 0, 0, 0);
      }
    }
  }

  // epilogue: divide by l (broadcast per C-row), coalesced f32 stores
  float* ob = out + (size_t)(b * 2048) * 768 + head * 64;
#pragma unroll
  for (int r = 0; r < 16; r++) {
    int q_r = (r & 3) + 8 * (r >> 2) + 4 * half;
    int li = __builtin_amdgcn_ds_bpermute(q_r << 2, __builtin_bit_cast(int, l_run));
    float inv = 1.0f / __builtin_bit_cast(float, li);
    size_t srow = (size_t)(q0 + q_r) * 768;
    ob[srow + lq] = oacc[0][r] * inv;
    ob[srow + 32 + lq] = oacc[1][r] * inv;
  }
}

// -------------------------------------------------------------------- launcher
extern "C" void kernel_launch(void* const* d_in, const int* in_sizes, int n_in,
                              void* d_out, int out_size, void* d_ws, size_t ws_size,
                              hipStream_t stream) {
  const float* hs = (const float*)d_in[0];
  const float* Wq = (const float*)d_in[1];
  const float* bq = (const float*)d_in[2];
  const float* Wk = (const float*)d_in[3];
  const float* bk = (const float*)d_in[4];
  const float* Wv = (const float*)d_in[5];
  const float* bv = (const float*)d_in[6];
  float* out = (float*)d_out;

  char* w = (char*)d_ws;
  bf16_t* hsb = (bf16_t*)w; w += (size_t)4096 * 768 * 2;   // 6.29 MB
  bf16_t* wtb = (bf16_t*)w; w += (size_t)2304 * 768 * 2;   // 3.54 MB
  bf16_t* Qb  = (bf16_t*)w; w += (size_t)24 * 2048 * 64 * 2;
  bf16_t* Kb  = (bf16_t*)w; w += (size_t)24 * 2048 * 64 * 2;
  bf16_t* VTb = (bf16_t*)w;                                 // total ~29 MB

  hipLaunchKernelGGL(cvt_hs, dim3(3072), dim3(256), 0, stream, hs, hsb);
  hipLaunchKernelGGL(cvt_w, dim3(72, 24), dim3(256), 0, stream, Wq, Wk, Wv, wtb);
  hipLaunchKernelGGL(gemm_qkv, dim3(18, 32), dim3(256), 0, stream, hsb, wtb, bq,
                     bk, bv, Qb, Kb, VTb);
  hipLaunchKernelGGL(attn, dim3(32, 24), dim3(128), 0, stream, Qb, Kb, VTb, out);
}